// Round 9
// baseline (95.301 us; speedup 1.0000x reference)
//
#include <hip/hip_runtime.h>
#include <hip/hip_fp16.h>

// ---------------------------------------------------------------------------
// ROUND 16: single-kernel fusion. Ledger: R12(2 disp)=92.2us, R13(3)=94.1,
// R15(3)=93.9 -- sim variants washed out by ~55us floor = 40us harness ws
// poison fill (uncontrollable) + ~15us launch gaps/dispatch overhead
// (controllable). Sim ~20us, finish ~6-8us. So: fuse everything into ONE
// dispatch. Grid = 4 + ceil(B/256) blocks x 256 thr:
//   blocks 0..3:  R15 sim (VERIFIED math, byte-identical), gate table
//                 computed in-block into LDS (R10-verified pattern+barrier),
//                 then: threadfence (agent: L2 writeback) -> release
//                 atomicAdd(flag).
//   blocks 4..:   precompute K-signs, spin on acquire load of flag until 4,
//                 threadfence (agent: L2 invalidate -- G16 cross-XCD
//                 correctness), then R15 finish math on 256-sample slice.
// Deadlock-free by co-residency: 36 blocks ~ 68.6KB LDS = 2 blocks/CU cap
// -> capacity ~512 >> 36, all resident regardless of dispatch order.
// flag (d_ws offset 0) zeroed via 4-byte hipMemsetAsync (graph-capturable,
// harness uses it itself). cols at d_ws+4096.
// Sim math recap (VERIFIED R14/R15, absmax 9.77e-4): S[m][n], m=wires0-5,
// n=wires6-11; S' = P_cnot(L S R^T); P_cnot folded into addressing:
//   U1 = S.R'^T (R' = gray6-rows of R); U2[k][n] = U1[k][n^63];
//   step2 transposed: W_x[n][m] = sum_k U_x^T[n][k] L[g6(m)][k];
//   S'[m][n] = W1 even m, W2 odd m.
// mfma_f32_32x32x16_f16; A: row=lane&31, k=8*(lane>>5)+i; B: col=lane&31;
// C/D: col=lane&31, row=(reg&3)+8*(reg>>2)+4*(lane>>5)  [HW m74/m101].
// f16 planes XOR-swizzled per 16B unit (unit ^= row&7).
// Rot entry: [[A-iB, -C-iD],[C-iD, A+iB]], A=ca*ch B=sa*ch C=cb*sh D=sb*sh.
// ---------------------------------------------------------------------------

typedef __half2 h2;
typedef _Float16 f16;
typedef __attribute__((ext_vector_type(8))) _Float16 f16x8;
typedef __attribute__((ext_vector_type(16))) float f32x16;

struct Gate32 { float a, b, c, d; };

#define SGN2 0x80008000
#define Z16 f32x16{0,0,0,0,0,0,0,0,0,0,0,0,0,0,0,0}

__device__ __forceinline__ float bpermf(int addr4, float v) {
    return __int_as_float(__builtin_amdgcn_ds_bpermute(addr4, __float_as_int(v)));
}
__device__ __forceinline__ int bci(h2 v)  { return __builtin_bit_cast(int, v); }
__device__ __forceinline__ h2 bch2(int v) { return __builtin_bit_cast(h2, v); }
__device__ __forceinline__ int g6(int x)  { return (x ^ (x >> 1)) & 63; }
__device__ __forceinline__ int moff(int row, int unit) {       // byte off in
    return row * 128 + ((unit ^ (row & 7)) << 4);              // f16[64][64]
}
__device__ __forceinline__ f16x8 fneg8(f16x8 v) {
    int4 x = __builtin_bit_cast(int4, v);
    x.x ^= SGN2; x.y ^= SGN2; x.z ^= SGN2; x.w ^= SGN2;
    return __builtin_bit_cast(f16x8, x);
}
__device__ __forceinline__ f32x16 MFMA(f16x8 a, f16x8 b, f32x16 c) {
    return __builtin_amdgcn_mfma_f32_32x32x16_f16(a, b, c, 0, 0, 0);
}

struct C2 { float r, i; };
__device__ __forceinline__ C2 cmul(C2 x, C2 y) {
    return { x.r*y.r - x.i*y.i, x.r*y.i + x.i*y.r };
}
// Rot entry (bi,bj): [[A-iB, -C-iD],[C-iD, A+iB]]
__device__ __forceinline__ C2 gent(const Gate32 g, int bi, int bj) {
    const float re = (bi == bj) ? g.a : (bi ? g.c : -g.c);
    const float im = (bi == bj) ? (bi ? g.b : -g.b) : -g.d;
    return { re, im };
}

// LDS layout (dynamic, 68608 B):
//   0..65536   : 8 f16[64][64] planes (Lr Li Rr Ri Sr Si Ur Ui)
//   65536      : KLr/KLi/KRr/KRi (4x64 f32 = 1024 B)
//   66560      : KLpr/KLpi/KRpr/KRpi (4x64 f16 = 512 B)
//   67072      : gt[96] Gate32 (1536 B)
__global__ __launch_bounds__(256, 1)
void fused_kernel(const float* __restrict__ wts,
                  const float* __restrict__ sb,
                  const float* __restrict__ hw,
                  const float* __restrict__ hb,
                  float* __restrict__ out,
                  int* __restrict__ flag,
                  float2* __restrict__ cols, int B) {
    extern __shared__ char smem[];
    const int tid = threadIdx.x;

    if (blockIdx.x < 4) {
        // ================= sim role (R15-verified, gt fused in-block) ======
        char* Lr = smem;
        char* Li = smem + 8192;
        char* Rr = smem + 16384;
        char* Ri = smem + 24576;
        char* Sr = smem + 32768;
        char* Si = smem + 40960;
        char* Ur = smem + 49152;
        char* Ui = smem + 57344;
        float* KLr = (float*)(smem + 65536);
        float* KLi = KLr + 64;  float* KRr = KLr + 128; float* KRi = KLr + 192;
        f16* KLpr = (f16*)(smem + 66560);
        f16* KLpi = KLpr + 64;  f16* KRpr = KLpr + 128; f16* KRpi = KLpr + 192;
        Gate32* gt = (Gate32*)(smem + 67072);

        const int lane = tid & 63;
        const int wid  = tid >> 6;
        const int b    = blockIdx.x;
        const int lo5  = lane & 31, hi = (lane >> 5) & 1;

        // ---- prologue: gate table (96 thr) + zero S planes; one barrier ---
        if (tid < 96) {
            const int l = tid / 12, w = tid % 12;
            const float* lw = wts + l*36 + w*3;
            float ch, sh, ca, sa, cb, sb_;
            __sincosf(0.5f*lw[1],         &sh, &ch);
            __sincosf(0.5f*(lw[0]+lw[2]), &sa, &ca);
            __sincosf(0.5f*(lw[0]-lw[2]), &sb_, &cb);
            Gate32 r; r.a = ca*ch; r.b = sa*ch; r.c = cb*sh; r.d = sb_*sh;
            gt[tid] = r;
        }
        {
            const int4 z = make_int4(0, 0, 0, 0);
#pragma unroll
            for (int u = 0; u < 2; ++u) {
                const int idx = u * 256 + tid;      // 512 units per plane
                const int row = idx >> 3, un = idx & 7;
                *(int4*)(Sr + moff(row, un)) = z;
                *(int4*)(Si + moff(row, un)) = z;
            }
        }
        __syncthreads();
        if (tid == 0) {
            const int row = 16 * b;
            *(f16*)(Sr + moff(row, 0)) = (f16)1.0f; // element (row, col 0)
        }
        __syncthreads();

#pragma unroll 1
        for (int l = 0; l < 8; ++l) {
            const Gate32* gl = gt + l * 12;
            // ---- phase A (wave 0): 8x8 Kronecker halves, lane = (ip,jp) ---
            if (tid < 64) {
                const int ip = tid >> 3, jp = tid & 7;
                const int i2 = (ip>>2)&1, i1 = (ip>>1)&1, i0 = ip&1;
                const int j2 = (jp>>2)&1, j1 = (jp>>1)&1, j0 = jp&1;
                const C2 kl  = cmul(cmul(gent(gl[0],i2,j2), gent(gl[1],i1,j1)), gent(gl[2],i0,j0));
                const C2 klp = cmul(cmul(gent(gl[3],i2,j2), gent(gl[4],i1,j1)), gent(gl[5],i0,j0));
                const C2 kr  = cmul(cmul(gent(gl[6],i2,j2), gent(gl[7],i1,j1)), gent(gl[8],i0,j0));
                const C2 krp = cmul(cmul(gent(gl[9],i2,j2), gent(gl[10],i1,j1)), gent(gl[11],i0,j0));
                KLr[tid] = kl.r;  KLi[tid] = kl.i;
                KRr[tid] = kr.r;  KRi[tid] = kr.i;
                KLpr[tid] = (f16)klp.r;  KLpi[tid] = (f16)klp.i;
                KRpr[tid] = (f16)krp.r;  KRpi[tid] = (f16)krp.i;
            }
            __syncthreads();
            // ---- phase B (all): row build. thread = (row, side, hk-half) --
            {
                const int r = tid & 63, rh = r >> 3, rl = r & 7;
                const int side = (tid >> 6) & 1;    // 0 = L, 1 = R
                const int hsel = tid >> 7;          // hk 0-3 or 4-7
                const float* xr4 = side ? (KRr + rh*8) : (KLr + rh*8);
                const float* xi4 = side ? (KRi + rh*8) : (KLi + rh*8);
                const int4 pyr = *(const int4*)((side ? KRpr : KLpr) + rl*8);
                const int4 pyi = *(const int4*)((side ? KRpi : KLpi) + rl*8);
                const h2 yr[4] = { bch2(pyr.x), bch2(pyr.y), bch2(pyr.z), bch2(pyr.w) };
                const h2 yi[4] = { bch2(pyi.x), bch2(pyi.y), bch2(pyi.z), bch2(pyi.w) };
                char* Pr = side ? Rr : Lr;
                char* Pi = side ? Ri : Li;
#pragma unroll
                for (int q = 0; q < 4; ++q) {
                    const int hk = 4*hsel + q;
                    const h2 xr2  = __float2half2_rn(xr4[hk]);
                    const h2 xi2  = __float2half2_rn(xi4[hk]);
                    const h2 nxi2 = bch2(bci(xi2) ^ SGN2);
                    h2 oR[4], oI[4];
#pragma unroll
                    for (int t = 0; t < 4; ++t) {
                        oR[t] = __hfma2(nxi2, yi[t], __hmul2(xr2, yr[t]));
                        oI[t] = __hfma2(xi2,  yr[t], __hmul2(xr2, yi[t]));
                    }
                    *(int4*)(Pr + moff(r, hk)) = make_int4(bci(oR[0]), bci(oR[1]), bci(oR[2]), bci(oR[3]));
                    *(int4*)(Pi + moff(r, hk)) = make_int4(bci(oI[0]), bci(oI[1]), bci(oI[2]), bci(oI[3]));
                }
            }
            __syncthreads();
            // ---- phase C (wave wid): step1 tile (mt,nt) = (wid>>1,wid&1) --
            {
                const int mt = wid >> 1, nt = wid & 1;
                f16x8 asr[4], asi[4], brr[4], bri[4];
                const int arow = 32*mt + lo5;
                const int brow = g6(32*nt + lo5);
#pragma unroll
                for (int kc = 0; kc < 4; ++kc) {
                    const int un = 2*kc + hi;
                    asr[kc] = *(const f16x8*)(Sr + moff(arow, un));
                    asi[kc] = *(const f16x8*)(Si + moff(arow, un));
                    brr[kc] = *(const f16x8*)(Rr + moff(brow, un));
                    bri[kc] = *(const f16x8*)(Ri + moff(brow, un));
                }
                f32x16 ur = Z16, ui = Z16;
#pragma unroll
                for (int kc = 0; kc < 4; ++kc) {
                    const f16x8 nri = fneg8(bri[kc]);
                    ur = MFMA(asr[kc], brr[kc], ur);   // Ur = Sr.Rr^T - Si.Ri^T
                    ur = MFMA(asi[kc], nri,     ur);
                    ui = MFMA(asr[kc], bri[kc], ui);   // Ui = Sr.Ri^T + Si.Rr^T
                    ui = MFMA(asi[kc], brr[kc], ui);
                }
                const int urow = 32*nt + lo5;          // write U^T[n][m]
#pragma unroll
                for (int gg = 0; gg < 4; ++gg) {
                    const h2 p0 = __floats2half2_rn(ur[4*gg+0], ur[4*gg+1]);
                    const h2 p1 = __floats2half2_rn(ur[4*gg+2], ur[4*gg+3]);
                    *(int2*)(Ur + moff(urow, 4*mt+gg) + 8*hi) = make_int2(bci(p0), bci(p1));
                    const h2 q0 = __floats2half2_rn(ui[4*gg+0], ui[4*gg+1]);
                    const h2 q1 = __floats2half2_rn(ui[4*gg+2], ui[4*gg+3]);
                    *(int2*)(Ui + moff(urow, 4*mt+gg) + 8*hi) = make_int2(bci(q0), bci(q1));
                }
            }
            __syncthreads();
            // ---- phase D (wave wid): step2 unit (nt2,mt2)=(wid>>1,wid&1) --
            {
                const int nt2 = wid >> 1, mt2 = wid & 1;
                f16x8 a1r[4], a1i[4], a2r[4], a2i[4];
                const int r1 = 32*nt2 + lo5, r2 = r1 ^ 63;  // U2 = row-flip
#pragma unroll
                for (int kc = 0; kc < 4; ++kc) {
                    const int un = 2*kc + hi;
                    a1r[kc] = *(const f16x8*)(Ur + moff(r1, un));
                    a1i[kc] = *(const f16x8*)(Ui + moff(r1, un));
                    a2r[kc] = *(const f16x8*)(Ur + moff(r2, un));
                    a2i[kc] = *(const f16x8*)(Ui + moff(r2, un));
                }
                const int m = 32*mt2 + lo5;
                const int lrow = g6(m);                     // folded row-gray
                f16x8 blr[4], bli[4];
#pragma unroll
                for (int kc = 0; kc < 4; ++kc) {
                    const int un = 2*kc + hi;
                    blr[kc] = *(const f16x8*)(Lr + moff(lrow, un));
                    bli[kc] = *(const f16x8*)(Li + moff(lrow, un));
                }
                f32x16 w1r = Z16, w1i = Z16, w2r = Z16, w2i = Z16;
#pragma unroll
                for (int kc = 0; kc < 4; ++kc) {
                    const f16x8 nbli = fneg8(bli[kc]);
                    w1r = MFMA(a1r[kc], blr[kc], w1r);
                    w1r = MFMA(a1i[kc], nbli,    w1r);
                    w1i = MFMA(a1r[kc], bli[kc], w1i);
                    w1i = MFMA(a1i[kc], blr[kc], w1i);
                    w2r = MFMA(a2r[kc], blr[kc], w2r);
                    w2r = MFMA(a2i[kc], nbli,    w2r);
                    w2i = MFMA(a2r[kc], bli[kc], w2i);
                    w2i = MFMA(a2i[kc], blr[kc], w2i);
                }
                const bool odd = (m & 1);
                if (l < 7) {                               // S'[m][n]
#pragma unroll
                    for (int gg = 0; gg < 4; ++gg) {
                        float s0 = odd ? w2r[4*gg+0] : w1r[4*gg+0];
                        float s1 = odd ? w2r[4*gg+1] : w1r[4*gg+1];
                        float s2 = odd ? w2r[4*gg+2] : w1r[4*gg+2];
                        float s3 = odd ? w2r[4*gg+3] : w1r[4*gg+3];
                        *(int2*)(Sr + moff(m, 4*nt2+gg) + 8*hi) =
                            make_int2(bci(__floats2half2_rn(s0, s1)),
                                      bci(__floats2half2_rn(s2, s3)));
                        s0 = odd ? w2i[4*gg+0] : w1i[4*gg+0];
                        s1 = odd ? w2i[4*gg+1] : w1i[4*gg+1];
                        s2 = odd ? w2i[4*gg+2] : w1i[4*gg+2];
                        s3 = odd ? w2i[4*gg+3] : w1i[4*gg+3];
                        *(int2*)(Si + moff(m, 4*nt2+gg) + 8*hi) =
                            make_int2(bci(__floats2half2_rn(s0, s1)),
                                      bci(__floats2half2_rn(s2, s3)));
                    }
                } else {                                   // final: f32 global
#pragma unroll
                    for (int gg = 0; gg < 4; ++gg)
#pragma unroll
                    for (int e = 0; e < 4; ++e) {
                        const int n = 32*nt2 + 8*gg + 4*hi + e;
                        const int r = 4*gg + e;
                        const float vr = odd ? w2r[r] : w1r[r];
                        const float vi = odd ? w2i[r] : w1i[r];
                        cols[b*4096 + (m << 6) + n] = make_float2(vr, vi);
                    }
                }
            }
            __syncthreads();
        }
        // ---- publish: L2 writeback (agent fence) then release add ----
        __threadfence();
        __syncthreads();
        if (tid == 0)
            __hip_atomic_fetch_add(flag, 1, __ATOMIC_RELEASE, __HIP_MEMORY_SCOPE_AGENT);

    } else {
        // ================= finish role (R15-verified math) =================
        float* gsh = (float*)smem;                  // [4][10]
        const int lane = tid & 63, wid = tid >> 6;

        float hwv[12];
#pragma unroll
        for (int w = 0; w < 12; ++w) hwv[w] = hw[w];

        float Klo = 0.f;                            // wires 4..11 (bits 7..0)
#pragma unroll
        for (int w = 4; w < 12; ++w)
            Klo += ((tid >> (11 - w)) & 1) ? -hwv[w] : hwv[w];

        // ---- wait for all 4 columns (acquire), then L2 invalidate ----
        if (tid == 0) {
            while (__hip_atomic_load(flag, __ATOMIC_ACQUIRE,
                                     __HIP_MEMORY_SCOPE_AGENT) < 4) {}
        }
        __syncthreads();
        __threadfence();                            // G16: invalidate stale L2

        float g[10];
#pragma unroll
        for (int m = 0; m < 10; ++m) g[m] = 0.f;

#pragma unroll 1
        for (int it = 0; it < 16; ++it) {
            const int q = (it << 8) | tid;
            const float2 c0 = cols[q];
            const float2 c1 = cols[4096  + q];
            const float2 c2 = cols[8192  + q];
            const float2 c3 = cols[12288 + q];
            float K = Klo;
#pragma unroll
            for (int w = 0; w < 4; ++w)             // wires 0..3: bits 11..8
                K += ((it >> (3 - w)) & 1) ? -hwv[w] : hwv[w];
            g[0] += K * (c0.x*c0.x + c0.y*c0.y);
            g[1] += K * (c1.x*c1.x + c1.y*c1.y);
            g[2] += K * (c2.x*c2.x + c2.y*c2.y);
            g[3] += K * (c3.x*c3.x + c3.y*c3.y);
            g[4] += K * (c0.x*c1.x + c0.y*c1.y);
            g[5] += K * (c2.x*c3.x + c2.y*c3.y);
            g[6] += K * (c0.x*c2.y - c0.y*c2.x);
            g[7] += K * (c0.x*c3.y - c0.y*c3.x);
            g[8] += K * (c1.x*c2.y - c1.y*c2.x);
            g[9] += K * (c1.x*c3.y - c1.y*c3.x);
        }

#pragma unroll
        for (int m = 0; m < 10; ++m) {
#pragma unroll
            for (int off = 1; off < 64; off <<= 1)
                g[m] += bpermf((lane ^ off) << 2, g[m]);
        }
        if (lane == 0) {
#pragma unroll
            for (int m = 0; m < 10; ++m) gsh[wid*10 + m] = g[m];
        }
        __syncthreads();
        float G[10];
#pragma unroll
        for (int m = 0; m < 10; ++m) {
            const float s = gsh[0*10+m] + gsh[1*10+m] + gsh[2*10+m] + gsh[3*10+m];
            G[m] = (m < 4) ? s : 2.f * s;           // fold 2*Re / 2*Im
        }

        const int i = (blockIdx.x - 4) * 256 + tid;
        if (i < B) {
            const float2 x = *reinterpret_cast<const float2*>(sb + i*8);
            float c0, s0, c1, s1;
            __sincosf(0.5f * x.x, &s0, &c0);
            __sincosf(0.5f * x.y, &s1, &c1);
            const float a0 = c0*c1, a1 = c0*s1, a2 = s0*c1, a3 = s0*s1;
            const float r = G[0]*a0*a0 + G[1]*a1*a1 + G[2]*a2*a2 + G[3]*a3*a3
                          + G[4]*(a0*a1) + G[5]*(a2*a3)
                          + G[6]*(a0*a2) + G[7]*(a0*a3)
                          + G[8]*(a1*a2) + G[9]*(a1*a3);
            out[i] = r + hb[0];
        }
    }
}

extern "C" void kernel_launch(void* const* d_in, const int* in_sizes, int n_in,
                              void* d_out, int out_size, void* d_ws, size_t ws_size,
                              hipStream_t stream) {
    const float* sb  = (const float*)d_in[0];
    const float* wts = (const float*)d_in[1];
    const float* hw  = (const float*)d_in[2];
    const float* hb  = (const float*)d_in[3];
    float* out = (float*)d_out;
    int*    flag = (int*)d_ws;                          // offset 0 (zeroed)
    float2* cols = (float2*)((char*)d_ws + 4096);       // 128 KB
    const int B = in_sizes[0] / 8;                      // (B,8) state_batch
    hipMemsetAsync(d_ws, 0, 4, stream);                 // flag = 0
    const int nfb = (B + 255) / 256;
    fused_kernel<<<4 + nfb, 256, 68608, stream>>>(wts, sb, hw, hb, out,
                                                  flag, cols, B);
}

// Round 10
// 89.409 us; speedup vs baseline: 1.0659x; 1.0659x over previous
//
#include <hip/hip_runtime.h>
#include <hip/hip_fp16.h>

// ---------------------------------------------------------------------------
// ROUND 17: consolidate to best-measured structure + sim latency squeeze.
// Ledger: R12(92.2) R13(94.1) R15(93.9) R16(95.3) -- plateau = 39.5us ws
// poison fill (268MB @85% HBM peak, harness-side, AT its roofline) + sim
// ~30-34 + finish ~7 + gaps. Only controllable term: sim. Three edits on the
// VERIFIED R15 math (algebra byte-identical):
//   1. gt table computed in-block (R16-verified prologue) -> 2 dispatches.
//   2. Phase A (Kron, wave-0-only) folded into tail of previous layer's
//      phase D (KL/KR buffers only read by next B; gt constant) ->
//      3 barriers/layer (was 4).
//   3. Phase C accumulators split by k-half (ur=ur0+ur1, ui=ui0+ui1):
//      dependent MFMA chains 8->4, ILP 2->4. At 1 wave/SIMD (68.6KB LDS ->
//      1 block/CU) ILP is the only latency hiding; D already ILP 4.
// Sim math recap (VERIFIED R14/R15/R16, absmax 9.77e-4): S[m][n],
// m=wires0-5, n=wires6-11; S' = P_cnot(L S R^T); P_cnot folded into
// addressing: U1 = S.R'^T (R' = gray6-rows of R); U2[k][n] = U1[k][n^63];
// step2 transposed: W_x[n][m] = sum_k U_x^T[n][k] L[g6(m)][k];
// S'[m][n] = W1 even m, W2 odd m.
// mfma_f32_32x32x16_f16; A: row=lane&31, k=8*(lane>>5)+i; B: col=lane&31;
// C/D: col=lane&31, row=(reg&3)+8*(reg>>2)+4*(lane>>5)  [HW m74/m101].
// f16 planes XOR-swizzled per 16B unit (unit ^= row&7).
// Rot entry: [[A-iB, -C-iD],[C-iD, A+iB]], A=ca*ch B=sa*ch C=cb*sh D=sb*sh.
// finish_kernel: verified R8+ unchanged.
// ---------------------------------------------------------------------------

typedef __half2 h2;
typedef _Float16 f16;
typedef __attribute__((ext_vector_type(8))) _Float16 f16x8;
typedef __attribute__((ext_vector_type(16))) float f32x16;

struct Gate32 { float a, b, c, d; };

#define SGN2 0x80008000
#define Z16 f32x16{0,0,0,0,0,0,0,0,0,0,0,0,0,0,0,0}

__device__ __forceinline__ float bpermf(int addr4, float v) {
    return __int_as_float(__builtin_amdgcn_ds_bpermute(addr4, __float_as_int(v)));
}
__device__ __forceinline__ int bci(h2 v)  { return __builtin_bit_cast(int, v); }
__device__ __forceinline__ h2 bch2(int v) { return __builtin_bit_cast(h2, v); }
__device__ __forceinline__ int g6(int x)  { return (x ^ (x >> 1)) & 63; }
__device__ __forceinline__ int moff(int row, int unit) {       // byte off in
    return row * 128 + ((unit ^ (row & 7)) << 4);              // f16[64][64]
}
__device__ __forceinline__ f16x8 fneg8(f16x8 v) {
    int4 x = __builtin_bit_cast(int4, v);
    x.x ^= SGN2; x.y ^= SGN2; x.z ^= SGN2; x.w ^= SGN2;
    return __builtin_bit_cast(f16x8, x);
}
__device__ __forceinline__ f32x16 MFMA(f16x8 a, f16x8 b, f32x16 c) {
    return __builtin_amdgcn_mfma_f32_32x32x16_f16(a, b, c, 0, 0, 0);
}

struct C2 { float r, i; };
__device__ __forceinline__ C2 cmul(C2 x, C2 y) {
    return { x.r*y.r - x.i*y.i, x.r*y.i + x.i*y.r };
}
// Rot entry (bi,bj): [[A-iB, -C-iD],[C-iD, A+iB]]
__device__ __forceinline__ C2 gent(const Gate32 g, int bi, int bj) {
    const float re = (bi == bj) ? g.a : (bi ? g.c : -g.c);
    const float im = (bi == bj) ? (bi ? g.b : -g.b) : -g.d;
    return { re, im };
}

// LDS layout (dynamic, 68608 B):
//   0..65536   : 8 f16[64][64] planes (Lr Li Rr Ri Sr Si Ur Ui)
//   65536      : KLr/KLi/KRr/KRi (4x64 f32 = 1024 B)
//   66560      : KLpr/KLpi/KRpr/KRpi (4x64 f16 = 512 B)
//   67072      : gt[96] Gate32 (1536 B)
__global__ __launch_bounds__(256, 1)
void sim_kernel(const float* __restrict__ wts, float2* __restrict__ cols) {
    extern __shared__ char smem[];
    char* Lr = smem;
    char* Li = smem + 8192;
    char* Rr = smem + 16384;
    char* Ri = smem + 24576;
    char* Sr = smem + 32768;
    char* Si = smem + 40960;
    char* Ur = smem + 49152;
    char* Ui = smem + 57344;
    float* KLr = (float*)(smem + 65536);
    float* KLi = KLr + 64;  float* KRr = KLr + 128; float* KRi = KLr + 192;
    f16* KLpr = (f16*)(smem + 66560);
    f16* KLpi = KLpr + 64;  f16* KRpr = KLpr + 128; f16* KRpi = KLpr + 192;
    Gate32* gt = (Gate32*)(smem + 67072);

    const int tid  = threadIdx.x;
    const int lane = tid & 63;
    const int wid  = tid >> 6;
    const int b    = blockIdx.x;
    const int lo5  = lane & 31, hi = (lane >> 5) & 1;

    // ---- prologue: gate table (96 thr) + zero S planes ----
    if (tid < 96) {
        const int l = tid / 12, w = tid % 12;
        const float* lw = wts + l*36 + w*3;
        float ch, sh, ca, sa, cb, sb_;
        __sincosf(0.5f*lw[1],         &sh, &ch);
        __sincosf(0.5f*(lw[0]+lw[2]), &sa, &ca);
        __sincosf(0.5f*(lw[0]-lw[2]), &sb_, &cb);
        Gate32 r; r.a = ca*ch; r.b = sa*ch; r.c = cb*sh; r.d = sb_*sh;
        gt[tid] = r;
    }
    {
        const int4 z = make_int4(0, 0, 0, 0);
#pragma unroll
        for (int u = 0; u < 2; ++u) {
            const int idx = u * 256 + tid;          // 512 units per plane
            const int row = idx >> 3, un = idx & 7;
            *(int4*)(Sr + moff(row, un)) = z;
            *(int4*)(Si + moff(row, un)) = z;
        }
    }
    __syncthreads();
    // ---- delta init + Kron(layer 0) (wave 0), one barrier ----
    if (tid == 0) {
        const int row = 16 * b;
        *(f16*)(Sr + moff(row, 0)) = (f16)1.0f;     // element (row, col 0)
    }
    if (tid < 64) {
        const Gate32* gl = gt;                      // layer 0
        const int ip = tid >> 3, jp = tid & 7;
        const int i2 = (ip>>2)&1, i1 = (ip>>1)&1, i0 = ip&1;
        const int j2 = (jp>>2)&1, j1 = (jp>>1)&1, j0 = jp&1;
        const C2 kl  = cmul(cmul(gent(gl[0],i2,j2), gent(gl[1],i1,j1)), gent(gl[2],i0,j0));
        const C2 klp = cmul(cmul(gent(gl[3],i2,j2), gent(gl[4],i1,j1)), gent(gl[5],i0,j0));
        const C2 kr  = cmul(cmul(gent(gl[6],i2,j2), gent(gl[7],i1,j1)), gent(gl[8],i0,j0));
        const C2 krp = cmul(cmul(gent(gl[9],i2,j2), gent(gl[10],i1,j1)), gent(gl[11],i0,j0));
        KLr[tid] = kl.r;  KLi[tid] = kl.i;
        KRr[tid] = kr.r;  KRi[tid] = kr.i;
        KLpr[tid] = (f16)klp.r;  KLpi[tid] = (f16)klp.i;
        KRpr[tid] = (f16)krp.r;  KRpi[tid] = (f16)krp.i;
    }
    __syncthreads();

#pragma unroll 1
    for (int l = 0; l < 8; ++l) {
        // ---- phase B (all): row build. thread = (row, side, hk-half) ----
        {
            const int r = tid & 63, rh = r >> 3, rl = r & 7;
            const int side = (tid >> 6) & 1;        // 0 = L, 1 = R
            const int hsel = tid >> 7;              // hk 0-3 or 4-7
            const float* xr4 = side ? (KRr + rh*8) : (KLr + rh*8);
            const float* xi4 = side ? (KRi + rh*8) : (KLi + rh*8);
            const int4 pyr = *(const int4*)((side ? KRpr : KLpr) + rl*8);
            const int4 pyi = *(const int4*)((side ? KRpi : KLpi) + rl*8);
            const h2 yr[4] = { bch2(pyr.x), bch2(pyr.y), bch2(pyr.z), bch2(pyr.w) };
            const h2 yi[4] = { bch2(pyi.x), bch2(pyi.y), bch2(pyi.z), bch2(pyi.w) };
            char* Pr = side ? Rr : Lr;
            char* Pi = side ? Ri : Li;
#pragma unroll
            for (int q = 0; q < 4; ++q) {
                const int hk = 4*hsel + q;
                const h2 xr2  = __float2half2_rn(xr4[hk]);
                const h2 xi2  = __float2half2_rn(xi4[hk]);
                const h2 nxi2 = bch2(bci(xi2) ^ SGN2);
                h2 oR[4], oI[4];
#pragma unroll
                for (int t = 0; t < 4; ++t) {
                    oR[t] = __hfma2(nxi2, yi[t], __hmul2(xr2, yr[t]));
                    oI[t] = __hfma2(xi2,  yr[t], __hmul2(xr2, yi[t]));
                }
                *(int4*)(Pr + moff(r, hk)) = make_int4(bci(oR[0]), bci(oR[1]), bci(oR[2]), bci(oR[3]));
                *(int4*)(Pi + moff(r, hk)) = make_int4(bci(oI[0]), bci(oI[1]), bci(oI[2]), bci(oI[3]));
            }
        }
        __syncthreads();
        // ---- phase C (wave wid): step1 tile (mt,nt); k-split ILP 4 ----
        {
            const int mt = wid >> 1, nt = wid & 1;
            f16x8 asr[4], asi[4], brr[4], bri[4];
            const int arow = 32*mt + lo5;
            const int brow = g6(32*nt + lo5);
#pragma unroll
            for (int kc = 0; kc < 4; ++kc) {
                const int un = 2*kc + hi;
                asr[kc] = *(const f16x8*)(Sr + moff(arow, un));
                asi[kc] = *(const f16x8*)(Si + moff(arow, un));
                brr[kc] = *(const f16x8*)(Rr + moff(brow, un));
                bri[kc] = *(const f16x8*)(Ri + moff(brow, un));
            }
            f32x16 ur0 = Z16, ur1 = Z16, ui0 = Z16, ui1 = Z16;
#pragma unroll
            for (int kc = 0; kc < 2; ++kc) {        // k-half 0 -> chains of 4
                const f16x8 nri = fneg8(bri[kc]);
                ur0 = MFMA(asr[kc], brr[kc], ur0);  // Ur = Sr.Rr^T - Si.Ri^T
                ur0 = MFMA(asi[kc], nri,     ur0);
                ui0 = MFMA(asr[kc], bri[kc], ui0);  // Ui = Sr.Ri^T + Si.Rr^T
                ui0 = MFMA(asi[kc], brr[kc], ui0);
            }
#pragma unroll
            for (int kc = 2; kc < 4; ++kc) {        // k-half 1
                const f16x8 nri = fneg8(bri[kc]);
                ur1 = MFMA(asr[kc], brr[kc], ur1);
                ur1 = MFMA(asi[kc], nri,     ur1);
                ui1 = MFMA(asr[kc], bri[kc], ui1);
                ui1 = MFMA(asi[kc], brr[kc], ui1);
            }
            const int urow = 32*nt + lo5;           // write U^T[n][m]
#pragma unroll
            for (int gg = 0; gg < 4; ++gg) {
                const h2 p0 = __floats2half2_rn(ur0[4*gg+0]+ur1[4*gg+0], ur0[4*gg+1]+ur1[4*gg+1]);
                const h2 p1 = __floats2half2_rn(ur0[4*gg+2]+ur1[4*gg+2], ur0[4*gg+3]+ur1[4*gg+3]);
                *(int2*)(Ur + moff(urow, 4*mt+gg) + 8*hi) = make_int2(bci(p0), bci(p1));
                const h2 q0 = __floats2half2_rn(ui0[4*gg+0]+ui1[4*gg+0], ui0[4*gg+1]+ui1[4*gg+1]);
                const h2 q1 = __floats2half2_rn(ui0[4*gg+2]+ui1[4*gg+2], ui0[4*gg+3]+ui1[4*gg+3]);
                *(int2*)(Ui + moff(urow, 4*mt+gg) + 8*hi) = make_int2(bci(q0), bci(q1));
            }
        }
        __syncthreads();
        // ---- phase D (wave wid): step2 unit (nt2,mt2) + folded Kron(l+1) --
        {
            const int nt2 = wid >> 1, mt2 = wid & 1;
            f16x8 a1r[4], a1i[4], a2r[4], a2i[4];
            const int r1 = 32*nt2 + lo5, r2 = r1 ^ 63;  // U2 = row-flip read
#pragma unroll
            for (int kc = 0; kc < 4; ++kc) {
                const int un = 2*kc + hi;
                a1r[kc] = *(const f16x8*)(Ur + moff(r1, un));
                a1i[kc] = *(const f16x8*)(Ui + moff(r1, un));
                a2r[kc] = *(const f16x8*)(Ur + moff(r2, un));
                a2i[kc] = *(const f16x8*)(Ui + moff(r2, un));
            }
            const int m = 32*mt2 + lo5;
            const int lrow = g6(m);                     // folded row-gray
            f16x8 blr[4], bli[4];
#pragma unroll
            for (int kc = 0; kc < 4; ++kc) {
                const int un = 2*kc + hi;
                blr[kc] = *(const f16x8*)(Lr + moff(lrow, un));
                bli[kc] = *(const f16x8*)(Li + moff(lrow, un));
            }
            f32x16 w1r = Z16, w1i = Z16, w2r = Z16, w2i = Z16;
#pragma unroll
            for (int kc = 0; kc < 4; ++kc) {            // 4 chains, ILP 4
                const f16x8 nbli = fneg8(bli[kc]);
                w1r = MFMA(a1r[kc], blr[kc], w1r);
                w1r = MFMA(a1i[kc], nbli,    w1r);
                w1i = MFMA(a1r[kc], bli[kc], w1i);
                w1i = MFMA(a1i[kc], blr[kc], w1i);
                w2r = MFMA(a2r[kc], blr[kc], w2r);
                w2r = MFMA(a2i[kc], nbli,    w2r);
                w2i = MFMA(a2r[kc], bli[kc], w2i);
                w2i = MFMA(a2i[kc], blr[kc], w2i);
            }
            const bool odd = (m & 1);
            if (l < 7) {                                // S'[m][n] row-major
#pragma unroll
                for (int gg = 0; gg < 4; ++gg) {
                    float s0 = odd ? w2r[4*gg+0] : w1r[4*gg+0];
                    float s1 = odd ? w2r[4*gg+1] : w1r[4*gg+1];
                    float s2 = odd ? w2r[4*gg+2] : w1r[4*gg+2];
                    float s3 = odd ? w2r[4*gg+3] : w1r[4*gg+3];
                    *(int2*)(Sr + moff(m, 4*nt2+gg) + 8*hi) =
                        make_int2(bci(__floats2half2_rn(s0, s1)),
                                  bci(__floats2half2_rn(s2, s3)));
                    s0 = odd ? w2i[4*gg+0] : w1i[4*gg+0];
                    s1 = odd ? w2i[4*gg+1] : w1i[4*gg+1];
                    s2 = odd ? w2i[4*gg+2] : w1i[4*gg+2];
                    s3 = odd ? w2i[4*gg+3] : w1i[4*gg+3];
                    *(int2*)(Si + moff(m, 4*nt2+gg) + 8*hi) =
                        make_int2(bci(__floats2half2_rn(s0, s1)),
                                  bci(__floats2half2_rn(s2, s3)));
                }
            } else {                                    // final: f32 global
#pragma unroll
                for (int gg = 0; gg < 4; ++gg)
#pragma unroll
                for (int e = 0; e < 4; ++e) {
                    const int n = 32*nt2 + 8*gg + 4*hi + e;
                    const int r = 4*gg + e;
                    const float vr = odd ? w2r[r] : w1r[r];
                    const float vi = odd ? w2i[r] : w1i[r];
                    cols[b*4096 + (m << 6) + n] = make_float2(vr, vi);
                }
            }
            // ---- folded Kron(l+1), wave 0 (KL/KR only read by next B) ----
            if (l < 7 && tid < 64) {
                const Gate32* gl2 = gt + (l+1) * 12;
                const int ip = tid >> 3, jp = tid & 7;
                const int i2 = (ip>>2)&1, i1 = (ip>>1)&1, i0 = ip&1;
                const int j2 = (jp>>2)&1, j1 = (jp>>1)&1, j0 = jp&1;
                const C2 kl  = cmul(cmul(gent(gl2[0],i2,j2), gent(gl2[1],i1,j1)), gent(gl2[2],i0,j0));
                const C2 klp = cmul(cmul(gent(gl2[3],i2,j2), gent(gl2[4],i1,j1)), gent(gl2[5],i0,j0));
                const C2 kr  = cmul(cmul(gent(gl2[6],i2,j2), gent(gl2[7],i1,j1)), gent(gl2[8],i0,j0));
                const C2 krp = cmul(cmul(gent(gl2[9],i2,j2), gent(gl2[10],i1,j1)), gent(gl2[11],i0,j0));
                KLr[tid] = kl.r;  KLi[tid] = kl.i;
                KRr[tid] = kr.r;  KRi[tid] = kr.i;
                KLpr[tid] = (f16)klp.r;  KLpi[tid] = (f16)klp.i;
                KRpr[tid] = (f16)krp.r;  KRpi[tid] = (f16)krp.i;
            }
        }
        __syncthreads();
    }
}

// ---- kernel 2: redundant G-reduce per block + per-sample quadratic form ---
__global__ __launch_bounds__(256)
void finish_kernel(const float* __restrict__ sb,
                   const float2* __restrict__ cols,
                   const float* __restrict__ hw,
                   const float* __restrict__ hb,
                   float* __restrict__ out, int B) {
    const int tid  = threadIdx.x;
    const int lane = tid & 63, wid = tid >> 6;

    float hwv[12];
#pragma unroll
    for (int w = 0; w < 12; ++w) hwv[w] = hw[w];

    float Klo = 0.f;
#pragma unroll
    for (int w = 4; w < 12; ++w)
        Klo += ((tid >> (11 - w)) & 1) ? -hwv[w] : hwv[w];

    float g[10];
#pragma unroll
    for (int m = 0; m < 10; ++m) g[m] = 0.f;

#pragma unroll 1
    for (int it = 0; it < 16; ++it) {
        const int q = (it << 8) | tid;
        const float2 c0 = cols[q];
        const float2 c1 = cols[4096  + q];
        const float2 c2 = cols[8192  + q];
        const float2 c3 = cols[12288 + q];
        float K = Klo;
#pragma unroll
        for (int w = 0; w < 4; ++w)
            K += ((it >> (3 - w)) & 1) ? -hwv[w] : hwv[w];
        g[0] += K * (c0.x*c0.x + c0.y*c0.y);
        g[1] += K * (c1.x*c1.x + c1.y*c1.y);
        g[2] += K * (c2.x*c2.x + c2.y*c2.y);
        g[3] += K * (c3.x*c3.x + c3.y*c3.y);
        g[4] += K * (c0.x*c1.x + c0.y*c1.y);
        g[5] += K * (c2.x*c3.x + c2.y*c3.y);
        g[6] += K * (c0.x*c2.y - c0.y*c2.x);
        g[7] += K * (c0.x*c3.y - c0.y*c3.x);
        g[8] += K * (c1.x*c2.y - c1.y*c2.x);
        g[9] += K * (c1.x*c3.y - c1.y*c3.x);
    }

    __shared__ float gsh[4][10];
#pragma unroll
    for (int m = 0; m < 10; ++m) {
#pragma unroll
        for (int off = 1; off < 64; off <<= 1)
            g[m] += bpermf((lane ^ off) << 2, g[m]);
    }
    if (lane == 0) {
#pragma unroll
        for (int m = 0; m < 10; ++m) gsh[wid][m] = g[m];
    }
    __syncthreads();
    float G[10];
#pragma unroll
    for (int m = 0; m < 10; ++m) {
        const float s = gsh[0][m] + gsh[1][m] + gsh[2][m] + gsh[3][m];
        G[m] = (m < 4) ? s : 2.f * s;
    }

    const int i = blockIdx.x * 256 + tid;
    if (i < B) {
        const float2 x = *reinterpret_cast<const float2*>(sb + i*8);
        float c0, s0, c1, s1;
        __sincosf(0.5f * x.x, &s0, &c0);
        __sincosf(0.5f * x.y, &s1, &c1);
        const float a0 = c0*c1, a1 = c0*s1, a2 = s0*c1, a3 = s0*s1;
        const float r = G[0]*a0*a0 + G[1]*a1*a1 + G[2]*a2*a2 + G[3]*a3*a3
                      + G[4]*(a0*a1) + G[5]*(a2*a3)
                      + G[6]*(a0*a2) + G[7]*(a0*a3)
                      + G[8]*(a1*a2) + G[9]*(a1*a3);
        out[i] = r + hb[0];
    }
}

extern "C" void kernel_launch(void* const* d_in, const int* in_sizes, int n_in,
                              void* d_out, int out_size, void* d_ws, size_t ws_size,
                              hipStream_t stream) {
    const float* sb  = (const float*)d_in[0];
    const float* wts = (const float*)d_in[1];
    const float* hw  = (const float*)d_in[2];
    const float* hb  = (const float*)d_in[3];
    float* out = (float*)d_out;
    float2* cols = (float2*)((char*)d_ws + 4096);       // 128 KB
    const int B = in_sizes[0] / 8;                      // (B,8) state_batch
    sim_kernel   <<<4, 256, 68608, stream>>>(wts, cols);
    finish_kernel<<<(B + 255)/256, 256, 0, stream>>>(sb, cols, hw, hb, out, B);
}

// Round 11
// 88.424 us; speedup vs baseline: 1.0778x; 1.0111x over previous
//
#include <hip/hip_runtime.h>
#include <hip/hip_fp16.h>

// ---------------------------------------------------------------------------
// ROUND 18: barrier diet + finish redundancy cut. R17 = 89.4us best.
// Ledger: 39.5us harness ws-poison fill (268MB @85% HBM peak -- AT its
// roofline, uncontrollable) + sim ~22-25 + finish ~7 + launch ~15.
// Two structural cuts, ZERO algebra changes (sim math VERIFIED R14-R17,
// absmax 9.77e-4):
//   1. Sim: 2 barriers/layer (was 3). L/R planes double-buffered by layer
//      parity (+32KB LDS -> 101KB dynamic; >64KB proven OK in R16; still
//      1 block/CU -- only 4 blocks exist). After-D barrier dropped:
//      D(l) reads L[par]/U; B(l+1) writes L[par^1] (disjoint planes);
//      Kron fold moved D-tail -> C-tail (wave 0) so B(l+1)'s KL reads are
//      protected by the after-C barrier. All RAW/WAR pairs in the straggler
//      window checked: B->C via bar(1), C->D via bar(2), D->C(l+1) via
//      bar(1) of l+1; KL: written C(l), read B(l+1), bar(2) between.
//   2. Finish: 8 blocks x 1024 thr (1 sample/thread, 4 q-iters) -- 4x less
//      redundant G-reduce; cross-wave reduce via 10 LDS atomicAdds/wave.
// Sim math recap: S[m][n], m=wires0-5, n=wires6-11; S' = P_cnot(L S R^T);
// P_cnot folded into addressing: U1 = S.R'^T (R' = gray6-rows of R);
// U2[k][n] = U1[k][n^63]; step2 transposed: W_x[n][m] = sum_k U_x^T[n][k]
// L[g6(m)][k]; S'[m][n] = W1 even m, W2 odd m.
// mfma_f32_32x32x16_f16; A: row=lane&31, k=8*(lane>>5)+i; B: col=lane&31;
// C/D: col=lane&31, row=(reg&3)+8*(reg>>2)+4*(lane>>5)  [HW m74/m101].
// f16 planes XOR-swizzled per 16B unit (unit ^= row&7).
// Rot entry: [[A-iB, -C-iD],[C-iD, A+iB]], A=ca*ch B=sa*ch C=cb*sh D=sb*sh.
// ---------------------------------------------------------------------------

typedef __half2 h2;
typedef _Float16 f16;
typedef __attribute__((ext_vector_type(8))) _Float16 f16x8;
typedef __attribute__((ext_vector_type(16))) float f32x16;

struct Gate32 { float a, b, c, d; };

#define SGN2 0x80008000
#define Z16 f32x16{0,0,0,0,0,0,0,0,0,0,0,0,0,0,0,0}

__device__ __forceinline__ float bpermf(int addr4, float v) {
    return __int_as_float(__builtin_amdgcn_ds_bpermute(addr4, __float_as_int(v)));
}
__device__ __forceinline__ int bci(h2 v)  { return __builtin_bit_cast(int, v); }
__device__ __forceinline__ h2 bch2(int v) { return __builtin_bit_cast(h2, v); }
__device__ __forceinline__ int g6(int x)  { return (x ^ (x >> 1)) & 63; }
__device__ __forceinline__ int moff(int row, int unit) {       // byte off in
    return row * 128 + ((unit ^ (row & 7)) << 4);              // f16[64][64]
}
__device__ __forceinline__ f16x8 fneg8(f16x8 v) {
    int4 x = __builtin_bit_cast(int4, v);
    x.x ^= SGN2; x.y ^= SGN2; x.z ^= SGN2; x.w ^= SGN2;
    return __builtin_bit_cast(f16x8, x);
}
__device__ __forceinline__ f32x16 MFMA(f16x8 a, f16x8 b, f32x16 c) {
    return __builtin_amdgcn_mfma_f32_32x32x16_f16(a, b, c, 0, 0, 0);
}

struct C2 { float r, i; };
__device__ __forceinline__ C2 cmul(C2 x, C2 y) {
    return { x.r*y.r - x.i*y.i, x.r*y.i + x.i*y.r };
}
// Rot entry (bi,bj): [[A-iB, -C-iD],[C-iD, A+iB]]
__device__ __forceinline__ C2 gent(const Gate32 g, int bi, int bj) {
    const float re = (bi == bj) ? g.a : (bi ? g.c : -g.c);
    const float im = (bi == bj) ? (bi ? g.b : -g.b) : -g.d;
    return { re, im };
}

// LDS layout (dynamic, 101376 B):
//   0        : L0r L0i R0r R0i  (4 x 8192 = 32768)
//   32768    : L1r L1i R1r R1i  (double buffer, layer parity)
//   65536    : Sr   73728: Si   81920: Ur   90112: Ui
//   98304    : KLr/KLi/KRr/KRi (4x64 f32 = 1024 B)
//   99328    : KLpr/KLpi/KRpr/KRpi (4x64 f16 = 512 B)
//   99840    : gt[96] Gate32 (1536 B)
__global__ __launch_bounds__(256, 1)
void sim_kernel(const float* __restrict__ wts, float2* __restrict__ cols) {
    extern __shared__ char smem[];
    char* Sr = smem + 65536;
    char* Si = smem + 73728;
    char* Ur = smem + 81920;
    char* Ui = smem + 90112;
    float* KLr = (float*)(smem + 98304);
    float* KLi = KLr + 64;  float* KRr = KLr + 128; float* KRi = KLr + 192;
    f16* KLpr = (f16*)(smem + 99328);
    f16* KLpi = KLpr + 64;  f16* KRpr = KLpr + 128; f16* KRpi = KLpr + 192;
    Gate32* gt = (Gate32*)(smem + 99840);

    const int tid  = threadIdx.x;
    const int lane = tid & 63;
    const int wid  = tid >> 6;
    const int b    = blockIdx.x;
    const int lo5  = lane & 31, hi = (lane >> 5) & 1;

    // ---- prologue: gate table (96 thr) + zero S planes ----
    if (tid < 96) {
        const int l = tid / 12, w = tid % 12;
        const float* lw = wts + l*36 + w*3;
        float ch, sh, ca, sa, cb, sb_;
        __sincosf(0.5f*lw[1],         &sh, &ch);
        __sincosf(0.5f*(lw[0]+lw[2]), &sa, &ca);
        __sincosf(0.5f*(lw[0]-lw[2]), &sb_, &cb);
        Gate32 r; r.a = ca*ch; r.b = sa*ch; r.c = cb*sh; r.d = sb_*sh;
        gt[tid] = r;
    }
    {
        const int4 z = make_int4(0, 0, 0, 0);
#pragma unroll
        for (int u = 0; u < 2; ++u) {
            const int idx = u * 256 + tid;          // 512 units per plane
            const int row = idx >> 3, un = idx & 7;
            *(int4*)(Sr + moff(row, un)) = z;
            *(int4*)(Si + moff(row, un)) = z;
        }
    }
    __syncthreads();
    // ---- delta init + Kron(layer 0) (wave 0), one barrier ----
    if (tid == 0) {
        const int row = 16 * b;
        *(f16*)(Sr + moff(row, 0)) = (f16)1.0f;     // element (row, col 0)
    }
    if (tid < 64) {
        const Gate32* gl = gt;                      // layer 0
        const int ip = tid >> 3, jp = tid & 7;
        const int i2 = (ip>>2)&1, i1 = (ip>>1)&1, i0 = ip&1;
        const int j2 = (jp>>2)&1, j1 = (jp>>1)&1, j0 = jp&1;
        const C2 kl  = cmul(cmul(gent(gl[0],i2,j2), gent(gl[1],i1,j1)), gent(gl[2],i0,j0));
        const C2 klp = cmul(cmul(gent(gl[3],i2,j2), gent(gl[4],i1,j1)), gent(gl[5],i0,j0));
        const C2 kr  = cmul(cmul(gent(gl[6],i2,j2), gent(gl[7],i1,j1)), gent(gl[8],i0,j0));
        const C2 krp = cmul(cmul(gent(gl[9],i2,j2), gent(gl[10],i1,j1)), gent(gl[11],i0,j0));
        KLr[tid] = kl.r;  KLi[tid] = kl.i;
        KRr[tid] = kr.r;  KRi[tid] = kr.i;
        KLpr[tid] = (f16)klp.r;  KLpi[tid] = (f16)klp.i;
        KRpr[tid] = (f16)krp.r;  KRpi[tid] = (f16)krp.i;
    }
    __syncthreads();

#pragma unroll 1
    for (int l = 0; l < 8; ++l) {
        char* Lr = smem + (l & 1) * 32768;          // layer-parity planes
        char* Li = Lr + 8192;
        char* Rr = Lr + 16384;
        char* Ri = Lr + 24576;
        // ---- phase B (all): row build. thread = (row, side, hk-half) ----
        {
            const int r = tid & 63, rh = r >> 3, rl = r & 7;
            const int side = (tid >> 6) & 1;        // 0 = L, 1 = R
            const int hsel = tid >> 7;              // hk 0-3 or 4-7
            const float* xr4 = side ? (KRr + rh*8) : (KLr + rh*8);
            const float* xi4 = side ? (KRi + rh*8) : (KLi + rh*8);
            const int4 pyr = *(const int4*)((side ? KRpr : KLpr) + rl*8);
            const int4 pyi = *(const int4*)((side ? KRpi : KLpi) + rl*8);
            const h2 yr[4] = { bch2(pyr.x), bch2(pyr.y), bch2(pyr.z), bch2(pyr.w) };
            const h2 yi[4] = { bch2(pyi.x), bch2(pyi.y), bch2(pyi.z), bch2(pyi.w) };
            char* Pr = side ? Rr : Lr;
            char* Pi = side ? Ri : Li;
#pragma unroll
            for (int q = 0; q < 4; ++q) {
                const int hk = 4*hsel + q;
                const h2 xr2  = __float2half2_rn(xr4[hk]);
                const h2 xi2  = __float2half2_rn(xi4[hk]);
                const h2 nxi2 = bch2(bci(xi2) ^ SGN2);
                h2 oR[4], oI[4];
#pragma unroll
                for (int t = 0; t < 4; ++t) {
                    oR[t] = __hfma2(nxi2, yi[t], __hmul2(xr2, yr[t]));
                    oI[t] = __hfma2(xi2,  yr[t], __hmul2(xr2, yi[t]));
                }
                *(int4*)(Pr + moff(r, hk)) = make_int4(bci(oR[0]), bci(oR[1]), bci(oR[2]), bci(oR[3]));
                *(int4*)(Pi + moff(r, hk)) = make_int4(bci(oI[0]), bci(oI[1]), bci(oI[2]), bci(oI[3]));
            }
        }
        __syncthreads();                            // bar(1): B -> C
        // ---- phase C (wave wid): step1 tile (mt,nt); k-split ILP 4 ----
        {
            const int mt = wid >> 1, nt = wid & 1;
            f16x8 asr[4], asi[4], brr[4], bri[4];
            const int arow = 32*mt + lo5;
            const int brow = g6(32*nt + lo5);
#pragma unroll
            for (int kc = 0; kc < 4; ++kc) {
                const int un = 2*kc + hi;
                asr[kc] = *(const f16x8*)(Sr + moff(arow, un));
                asi[kc] = *(const f16x8*)(Si + moff(arow, un));
                brr[kc] = *(const f16x8*)(Rr + moff(brow, un));
                bri[kc] = *(const f16x8*)(Ri + moff(brow, un));
            }
            f32x16 ur0 = Z16, ur1 = Z16, ui0 = Z16, ui1 = Z16;
#pragma unroll
            for (int kc = 0; kc < 2; ++kc) {        // k-half 0 -> chains of 4
                const f16x8 nri = fneg8(bri[kc]);
                ur0 = MFMA(asr[kc], brr[kc], ur0);  // Ur = Sr.Rr^T - Si.Ri^T
                ur0 = MFMA(asi[kc], nri,     ur0);
                ui0 = MFMA(asr[kc], bri[kc], ui0);  // Ui = Sr.Ri^T + Si.Rr^T
                ui0 = MFMA(asi[kc], brr[kc], ui0);
            }
#pragma unroll
            for (int kc = 2; kc < 4; ++kc) {        // k-half 1
                const f16x8 nri = fneg8(bri[kc]);
                ur1 = MFMA(asr[kc], brr[kc], ur1);
                ur1 = MFMA(asi[kc], nri,     ur1);
                ui1 = MFMA(asr[kc], bri[kc], ui1);
                ui1 = MFMA(asi[kc], brr[kc], ui1);
            }
            const int urow = 32*nt + lo5;           // write U^T[n][m]
#pragma unroll
            for (int gg = 0; gg < 4; ++gg) {
                const h2 p0 = __floats2half2_rn(ur0[4*gg+0]+ur1[4*gg+0], ur0[4*gg+1]+ur1[4*gg+1]);
                const h2 p1 = __floats2half2_rn(ur0[4*gg+2]+ur1[4*gg+2], ur0[4*gg+3]+ur1[4*gg+3]);
                *(int2*)(Ur + moff(urow, 4*mt+gg) + 8*hi) = make_int2(bci(p0), bci(p1));
                const h2 q0 = __floats2half2_rn(ui0[4*gg+0]+ui1[4*gg+0], ui0[4*gg+1]+ui1[4*gg+1]);
                const h2 q1 = __floats2half2_rn(ui0[4*gg+2]+ui1[4*gg+2], ui0[4*gg+3]+ui1[4*gg+3]);
                *(int2*)(Ui + moff(urow, 4*mt+gg) + 8*hi) = make_int2(bci(q0), bci(q1));
            }
            // ---- folded Kron(l+1), wave 0 (KL last read in B(l), pre-bar1;
            //      B(l+1) reads it after bar(2)) ----
            if (l < 7 && tid < 64) {
                const Gate32* gl2 = gt + (l+1) * 12;
                const int ip = tid >> 3, jp = tid & 7;
                const int i2 = (ip>>2)&1, i1 = (ip>>1)&1, i0 = ip&1;
                const int j2 = (jp>>2)&1, j1 = (jp>>1)&1, j0 = jp&1;
                const C2 kl  = cmul(cmul(gent(gl2[0],i2,j2), gent(gl2[1],i1,j1)), gent(gl2[2],i0,j0));
                const C2 klp = cmul(cmul(gent(gl2[3],i2,j2), gent(gl2[4],i1,j1)), gent(gl2[5],i0,j0));
                const C2 kr  = cmul(cmul(gent(gl2[6],i2,j2), gent(gl2[7],i1,j1)), gent(gl2[8],i0,j0));
                const C2 krp = cmul(cmul(gent(gl2[9],i2,j2), gent(gl2[10],i1,j1)), gent(gl2[11],i0,j0));
                KLr[tid] = kl.r;  KLi[tid] = kl.i;
                KRr[tid] = kr.r;  KRi[tid] = kr.i;
                KLpr[tid] = (f16)klp.r;  KLpi[tid] = (f16)klp.i;
                KRpr[tid] = (f16)krp.r;  KRpi[tid] = (f16)krp.i;
            }
        }
        __syncthreads();                            // bar(2): C -> D
        // ---- phase D (wave wid): step2 unit (nt2,mt2); NO trailing bar ----
        {
            const int nt2 = wid >> 1, mt2 = wid & 1;
            f16x8 a1r[4], a1i[4], a2r[4], a2i[4];
            const int r1 = 32*nt2 + lo5, r2 = r1 ^ 63;  // U2 = row-flip read
#pragma unroll
            for (int kc = 0; kc < 4; ++kc) {
                const int un = 2*kc + hi;
                a1r[kc] = *(const f16x8*)(Ur + moff(r1, un));
                a1i[kc] = *(const f16x8*)(Ui + moff(r1, un));
                a2r[kc] = *(const f16x8*)(Ur + moff(r2, un));
                a2i[kc] = *(const f16x8*)(Ui + moff(r2, un));
            }
            const int m = 32*mt2 + lo5;
            const int lrow = g6(m);                     // folded row-gray
            f16x8 blr[4], bli[4];
#pragma unroll
            for (int kc = 0; kc < 4; ++kc) {
                const int un = 2*kc + hi;
                blr[kc] = *(const f16x8*)(Lr + moff(lrow, un));
                bli[kc] = *(const f16x8*)(Li + moff(lrow, un));
            }
            f32x16 w1r = Z16, w1i = Z16, w2r = Z16, w2i = Z16;
#pragma unroll
            for (int kc = 0; kc < 4; ++kc) {            // 4 chains, ILP 4
                const f16x8 nbli = fneg8(bli[kc]);
                w1r = MFMA(a1r[kc], blr[kc], w1r);
                w1r = MFMA(a1i[kc], nbli,    w1r);
                w1i = MFMA(a1r[kc], bli[kc], w1i);
                w1i = MFMA(a1i[kc], blr[kc], w1i);
                w2r = MFMA(a2r[kc], blr[kc], w2r);
                w2r = MFMA(a2i[kc], nbli,    w2r);
                w2i = MFMA(a2r[kc], bli[kc], w2i);
                w2i = MFMA(a2i[kc], blr[kc], w2i);
            }
            const bool odd = (m & 1);
            if (l < 7) {                                // S'[m][n] row-major
#pragma unroll
                for (int gg = 0; gg < 4; ++gg) {
                    float s0 = odd ? w2r[4*gg+0] : w1r[4*gg+0];
                    float s1 = odd ? w2r[4*gg+1] : w1r[4*gg+1];
                    float s2 = odd ? w2r[4*gg+2] : w1r[4*gg+2];
                    float s3 = odd ? w2r[4*gg+3] : w1r[4*gg+3];
                    *(int2*)(Sr + moff(m, 4*nt2+gg) + 8*hi) =
                        make_int2(bci(__floats2half2_rn(s0, s1)),
                                  bci(__floats2half2_rn(s2, s3)));
                    s0 = odd ? w2i[4*gg+0] : w1i[4*gg+0];
                    s1 = odd ? w2i[4*gg+1] : w1i[4*gg+1];
                    s2 = odd ? w2i[4*gg+2] : w1i[4*gg+2];
                    s3 = odd ? w2i[4*gg+3] : w1i[4*gg+3];
                    *(int2*)(Si + moff(m, 4*nt2+gg) + 8*hi) =
                        make_int2(bci(__floats2half2_rn(s0, s1)),
                                  bci(__floats2half2_rn(s2, s3)));
                }
            } else {                                    // final: f32 global
#pragma unroll
                for (int gg = 0; gg < 4; ++gg)
#pragma unroll
                for (int e = 0; e < 4; ++e) {
                    const int n = 32*nt2 + 8*gg + 4*hi + e;
                    const int r = 4*gg + e;
                    const float vr = odd ? w2r[r] : w1r[r];
                    const float vi = odd ? w2i[r] : w1i[r];
                    cols[b*4096 + (m << 6) + n] = make_float2(vr, vi);
                }
            }
        }
        // no barrier: D reads {U, L[par]}, writes S; next B writes L[par^1],
        // reads KL (written in C, bar(2) between). Next C gated by bar(1).
    }
}

// ---- kernel 2: G-reduce (8 blocks, 4x less redundancy) + quadratic form ---
__global__ __launch_bounds__(1024)
void finish_kernel(const float* __restrict__ sb,
                   const float2* __restrict__ cols,
                   const float* __restrict__ hw,
                   const float* __restrict__ hb,
                   float* __restrict__ out, int B) {
    __shared__ float Gsh[10];
    const int tid  = threadIdx.x;
    const int lane = tid & 63;

    if (tid < 10) Gsh[tid] = 0.f;

    float hwv[12];
#pragma unroll
    for (int w = 0; w < 12; ++w) hwv[w] = hw[w];

    // K(q) split: q = (it<<10) | tid -> Klo over wires 2..11 (bits 9..0)
    float Klo = 0.f;
#pragma unroll
    for (int w = 2; w < 12; ++w)
        Klo += ((tid >> (11 - w)) & 1) ? -hwv[w] : hwv[w];

    __syncthreads();                                // Gsh zero visible

    float g[10];
#pragma unroll
    for (int m = 0; m < 10; ++m) g[m] = 0.f;

#pragma unroll 1
    for (int it = 0; it < 4; ++it) {
        const int q = (it << 10) | tid;
        const float2 c0 = cols[q];
        const float2 c1 = cols[4096  + q];
        const float2 c2 = cols[8192  + q];
        const float2 c3 = cols[12288 + q];
        float K = Klo;
        K += ((it >> 1) & 1) ? -hwv[0] : hwv[0];    // wire 0 <-> bit 11
        K += (it & 1)        ? -hwv[1] : hwv[1];    // wire 1 <-> bit 10
        g[0] += K * (c0.x*c0.x + c0.y*c0.y);
        g[1] += K * (c1.x*c1.x + c1.y*c1.y);
        g[2] += K * (c2.x*c2.x + c2.y*c2.y);
        g[3] += K * (c3.x*c3.x + c3.y*c3.y);
        g[4] += K * (c0.x*c1.x + c0.y*c1.y);
        g[5] += K * (c2.x*c3.x + c2.y*c3.y);
        g[6] += K * (c0.x*c2.y - c0.y*c2.x);
        g[7] += K * (c0.x*c3.y - c0.y*c3.x);
        g[8] += K * (c1.x*c2.y - c1.y*c2.x);
        g[9] += K * (c1.x*c3.y - c1.y*c3.x);
    }

    // wave butterfly -> every lane holds wave-sum; lane m adds to Gsh[m]
#pragma unroll
    for (int m = 0; m < 10; ++m) {
#pragma unroll
        for (int off = 1; off < 64; off <<= 1)
            g[m] += bpermf((lane ^ off) << 2, g[m]);
    }
#pragma unroll
    for (int m = 0; m < 10; ++m)
        if (lane == m) atomicAdd(&Gsh[m], g[m]);
    __syncthreads();

    float G[10];
#pragma unroll
    for (int m = 0; m < 10; ++m)
        G[m] = ((m < 4) ? 1.f : 2.f) * Gsh[m];      // fold 2*Re / 2*Im

    const int i = blockIdx.x * 1024 + tid;
    if (i < B) {
        const float2 x = *reinterpret_cast<const float2*>(sb + i*8);
        float c0, s0, c1, s1;
        __sincosf(0.5f * x.x, &s0, &c0);
        __sincosf(0.5f * x.y, &s1, &c1);
        const float a0 = c0*c1, a1 = c0*s1, a2 = s0*c1, a3 = s0*s1;
        const float r = G[0]*a0*a0 + G[1]*a1*a1 + G[2]*a2*a2 + G[3]*a3*a3
                      + G[4]*(a0*a1) + G[5]*(a2*a3)
                      + G[6]*(a0*a2) + G[7]*(a0*a3)
                      + G[8]*(a1*a2) + G[9]*(a1*a3);
        out[i] = r + hb[0];
    }
}

extern "C" void kernel_launch(void* const* d_in, const int* in_sizes, int n_in,
                              void* d_out, int out_size, void* d_ws, size_t ws_size,
                              hipStream_t stream) {
    const float* sb  = (const float*)d_in[0];
    const float* wts = (const float*)d_in[1];
    const float* hw  = (const float*)d_in[2];
    const float* hb  = (const float*)d_in[3];
    float* out = (float*)d_out;
    float2* cols = (float2*)((char*)d_ws + 4096);       // 128 KB
    const int B = in_sizes[0] / 8;                      // (B,8) state_batch
    sim_kernel   <<<4, 256, 101376, stream>>>(wts, cols);
    finish_kernel<<<(B + 1023)/1024, 1024, 0, stream>>>(sb, cols, hw, hb, out, B);
}

// Round 12
// 84.924 us; speedup vs baseline: 1.1222x; 1.0412x over previous
//
#include <hip/hip_runtime.h>
#include <hip/hip_fp16.h>

// ---------------------------------------------------------------------------
// ROUND 19: 2 waves/SIMD. R18 = 88.4us; sim ran 4 waves on 4 SIMDs/CU ->
// zero TLP per SIMD; every ds_read_b128 (~120cy) + MFMA chain tail hidden
// only by per-wave ILP. This round: 512-thread sim (8 waves = 2/SIMD),
// SAME algebra (VERIFIED R14-R18, absmax 9.77e-4), work split doubled:
//   B: 512 thr = (row, side, hk-quarter), 2 units/thread (was 4)
//   C: 8 waves = (tile x {re,im}); bX = ri? bri:brr, bY = ri? brr:-bri
//      (exactly ur/ui's verified forms); disjoint plane writes (Ur vs Ui)
//   D: 8 waves = (unit x {W1,W2}); parity wave px reads r1 or r1^63,
//      writes only lanes with m&1==px (same per-lane parity select as
//      before, as a predicated write; union = old coverage, no overlap)
// Kron fold stays wave 0, C-tail. 2 barriers/layer unchanged. Per-SIMD MFMA
// work unchanged; 2 waves now cross-hide DS latency + chain tails.
// Math recap: S[m][n], m=wires0-5, n=wires6-11; S' = P_cnot(L S R^T);
// P_cnot folded: U1 = S.R'^T (R' = gray6-rows); U2[k][n] = U1[k][n^63];
// step2 transposed: W_x[n][m] = sum_k U_x^T[n][k] L[g6(m)][k];
// S'[m][n] = W1 even m, W2 odd m.
// mfma_f32_32x32x16_f16; A: row=lane&31, k=8*(lane>>5)+i; B: col=lane&31;
// C/D: col=lane&31, row=(reg&3)+8*(reg>>2)+4*(lane>>5)  [HW m74/m101].
// f16 planes XOR-swizzled per 16B unit (unit ^= row&7).
// Rot entry: [[A-iB, -C-iD],[C-iD, A+iB]], A=ca*ch B=sa*ch C=cb*sh D=sb*sh.
// finish_kernel: R18 (8 blocks x 1024) unchanged.
// DECISION RULE: >=88us => plateau = 39.5 fill (85% HBM peak) + ~20 harness
// dispatch overhead + ~18 sim latency floor (4 columns x sequential layers)
// => ROOFLINE.
// ---------------------------------------------------------------------------

typedef __half2 h2;
typedef _Float16 f16;
typedef __attribute__((ext_vector_type(8))) _Float16 f16x8;
typedef __attribute__((ext_vector_type(16))) float f32x16;

struct Gate32 { float a, b, c, d; };

#define SGN2 0x80008000
#define Z16 f32x16{0,0,0,0,0,0,0,0,0,0,0,0,0,0,0,0}

__device__ __forceinline__ float bpermf(int addr4, float v) {
    return __int_as_float(__builtin_amdgcn_ds_bpermute(addr4, __float_as_int(v)));
}
__device__ __forceinline__ int bci(h2 v)  { return __builtin_bit_cast(int, v); }
__device__ __forceinline__ h2 bch2(int v) { return __builtin_bit_cast(h2, v); }
__device__ __forceinline__ int g6(int x)  { return (x ^ (x >> 1)) & 63; }
__device__ __forceinline__ int moff(int row, int unit) {       // byte off in
    return row * 128 + ((unit ^ (row & 7)) << 4);              // f16[64][64]
}
__device__ __forceinline__ f16x8 fneg8(f16x8 v) {
    int4 x = __builtin_bit_cast(int4, v);
    x.x ^= SGN2; x.y ^= SGN2; x.z ^= SGN2; x.w ^= SGN2;
    return __builtin_bit_cast(f16x8, x);
}
__device__ __forceinline__ f32x16 MFMA(f16x8 a, f16x8 b, f32x16 c) {
    return __builtin_amdgcn_mfma_f32_32x32x16_f16(a, b, c, 0, 0, 0);
}

struct C2 { float r, i; };
__device__ __forceinline__ C2 cmul(C2 x, C2 y) {
    return { x.r*y.r - x.i*y.i, x.r*y.i + x.i*y.r };
}
// Rot entry (bi,bj): [[A-iB, -C-iD],[C-iD, A+iB]]
__device__ __forceinline__ C2 gent(const Gate32 g, int bi, int bj) {
    const float re = (bi == bj) ? g.a : (bi ? g.c : -g.c);
    const float im = (bi == bj) ? (bi ? g.b : -g.b) : -g.d;
    return { re, im };
}

// LDS layout (dynamic, 101376 B):
//   0        : L0r L0i R0r R0i  (4 x 8192 = 32768)
//   32768    : L1r L1i R1r R1i  (double buffer, layer parity)
//   65536    : Sr   73728: Si   81920: Ur   90112: Ui
//   98304    : KLr/KLi/KRr/KRi (4x64 f32 = 1024 B)
//   99328    : KLpr/KLpi/KRpr/KRpi (4x64 f16 = 512 B)
//   99840    : gt[96] Gate32 (1536 B)
__global__ __launch_bounds__(512, 1)
void sim_kernel(const float* __restrict__ wts, float2* __restrict__ cols) {
    extern __shared__ char smem[];
    char* Sr = smem + 65536;
    char* Si = smem + 73728;
    char* Ur = smem + 81920;
    char* Ui = smem + 90112;
    float* KLr = (float*)(smem + 98304);
    float* KLi = KLr + 64;  float* KRr = KLr + 128; float* KRi = KLr + 192;
    f16* KLpr = (f16*)(smem + 99328);
    f16* KLpi = KLpr + 64;  f16* KRpr = KLpr + 128; f16* KRpi = KLpr + 192;
    Gate32* gt = (Gate32*)(smem + 99840);

    const int tid  = threadIdx.x;
    const int lane = tid & 63;
    const int wid  = tid >> 6;                      // 0..7
    const int b    = blockIdx.x;
    const int lo5  = lane & 31, hi = (lane >> 5) & 1;

    // ---- prologue: gate table (96 thr) + zero S planes ----
    if (tid < 96) {
        const int l = tid / 12, w = tid % 12;
        const float* lw = wts + l*36 + w*3;
        float ch, sh, ca, sa, cb, sb_;
        __sincosf(0.5f*lw[1],         &sh, &ch);
        __sincosf(0.5f*(lw[0]+lw[2]), &sa, &ca);
        __sincosf(0.5f*(lw[0]-lw[2]), &sb_, &cb);
        Gate32 r; r.a = ca*ch; r.b = sa*ch; r.c = cb*sh; r.d = sb_*sh;
        gt[tid] = r;
    }
    {
        const int4 z = make_int4(0, 0, 0, 0);
        const int row = tid >> 3, un = tid & 7;     // 512 units per plane
        *(int4*)(Sr + moff(row, un)) = z;
        *(int4*)(Si + moff(row, un)) = z;
    }
    __syncthreads();
    // ---- delta init + Kron(layer 0) (wave 0), one barrier ----
    if (tid == 0) {
        const int row = 16 * b;
        *(f16*)(Sr + moff(row, 0)) = (f16)1.0f;     // element (row, col 0)
    }
    if (tid < 64) {
        const Gate32* gl = gt;                      // layer 0
        const int ip = tid >> 3, jp = tid & 7;
        const int i2 = (ip>>2)&1, i1 = (ip>>1)&1, i0 = ip&1;
        const int j2 = (jp>>2)&1, j1 = (jp>>1)&1, j0 = jp&1;
        const C2 kl  = cmul(cmul(gent(gl[0],i2,j2), gent(gl[1],i1,j1)), gent(gl[2],i0,j0));
        const C2 klp = cmul(cmul(gent(gl[3],i2,j2), gent(gl[4],i1,j1)), gent(gl[5],i0,j0));
        const C2 kr  = cmul(cmul(gent(gl[6],i2,j2), gent(gl[7],i1,j1)), gent(gl[8],i0,j0));
        const C2 krp = cmul(cmul(gent(gl[9],i2,j2), gent(gl[10],i1,j1)), gent(gl[11],i0,j0));
        KLr[tid] = kl.r;  KLi[tid] = kl.i;
        KRr[tid] = kr.r;  KRi[tid] = kr.i;
        KLpr[tid] = (f16)klp.r;  KLpi[tid] = (f16)klp.i;
        KRpr[tid] = (f16)krp.r;  KRpi[tid] = (f16)krp.i;
    }
    __syncthreads();

#pragma unroll 1
    for (int l = 0; l < 8; ++l) {
        char* Lr = smem + (l & 1) * 32768;          // layer-parity planes
        char* Li = Lr + 8192;
        char* Rr = Lr + 16384;
        char* Ri = Lr + 24576;
        // ---- phase B: 512 thr = (row, side, hk-quarter), 2 units each ----
        {
            const int r = tid & 63, rh = r >> 3, rl = r & 7;
            const int side = (tid >> 6) & 1;        // 0 = L, 1 = R
            const int hsel = tid >> 7;              // 0..3 -> hk pair
            const float* xr4 = side ? (KRr + rh*8) : (KLr + rh*8);
            const float* xi4 = side ? (KRi + rh*8) : (KLi + rh*8);
            const int4 pyr = *(const int4*)((side ? KRpr : KLpr) + rl*8);
            const int4 pyi = *(const int4*)((side ? KRpi : KLpi) + rl*8);
            const h2 yr[4] = { bch2(pyr.x), bch2(pyr.y), bch2(pyr.z), bch2(pyr.w) };
            const h2 yi[4] = { bch2(pyi.x), bch2(pyi.y), bch2(pyi.z), bch2(pyi.w) };
            char* Pr = side ? Rr : Lr;
            char* Pi = side ? Ri : Li;
#pragma unroll
            for (int q = 0; q < 2; ++q) {
                const int hk = 2*hsel + q;
                const h2 xr2  = __float2half2_rn(xr4[hk]);
                const h2 xi2  = __float2half2_rn(xi4[hk]);
                const h2 nxi2 = bch2(bci(xi2) ^ SGN2);
                h2 oR[4], oI[4];
#pragma unroll
                for (int t = 0; t < 4; ++t) {
                    oR[t] = __hfma2(nxi2, yi[t], __hmul2(xr2, yr[t]));
                    oI[t] = __hfma2(xi2,  yr[t], __hmul2(xr2, yi[t]));
                }
                *(int4*)(Pr + moff(r, hk)) = make_int4(bci(oR[0]), bci(oR[1]), bci(oR[2]), bci(oR[3]));
                *(int4*)(Pi + moff(r, hk)) = make_int4(bci(oI[0]), bci(oI[1]), bci(oI[2]), bci(oI[3]));
            }
        }
        __syncthreads();                            // bar(1): B -> C
        // ---- phase C: 8 waves = (tile x {re,im}); k-split ILP ----
        {
            const int tile = wid >> 1;              // 0..3
            const int mt = tile >> 1, nt = tile & 1;
            const int ri = wid & 1;                 // 0 = Ur, 1 = Ui
            f16x8 asr[4], asi[4], bX[4], bY[4];
            const int arow = 32*mt + lo5;
            const int brow = g6(32*nt + lo5);
#pragma unroll
            for (int kc = 0; kc < 4; ++kc) {
                const int un = 2*kc + hi;
                asr[kc] = *(const f16x8*)(Sr + moff(arow, un));
                asi[kc] = *(const f16x8*)(Si + moff(arow, un));
                const f16x8 brr = *(const f16x8*)(Rr + moff(brow, un));
                const f16x8 bri = *(const f16x8*)(Ri + moff(brow, un));
                // ur = asr.brr + asi.(-bri) ; ui = asr.bri + asi.brr
                bX[kc] = ri ? bri : brr;
                bY[kc] = ri ? brr : fneg8(bri);
            }
            f32x16 u0 = Z16, u1 = Z16;
#pragma unroll
            for (int kc = 0; kc < 2; ++kc) {        // k-half 0: chains of 4
                u0 = MFMA(asr[kc], bX[kc], u0);
                u0 = MFMA(asi[kc], bY[kc], u0);
            }
#pragma unroll
            for (int kc = 2; kc < 4; ++kc) {        // k-half 1
                u1 = MFMA(asr[kc], bX[kc], u1);
                u1 = MFMA(asi[kc], bY[kc], u1);
            }
            char* Up = ri ? Ui : Ur;                // disjoint plane per wave
            const int urow = 32*nt + lo5;           // write U^T[n][m]
#pragma unroll
            for (int gg = 0; gg < 4; ++gg) {
                const h2 p0 = __floats2half2_rn(u0[4*gg+0]+u1[4*gg+0], u0[4*gg+1]+u1[4*gg+1]);
                const h2 p1 = __floats2half2_rn(u0[4*gg+2]+u1[4*gg+2], u0[4*gg+3]+u1[4*gg+3]);
                *(int2*)(Up + moff(urow, 4*mt+gg) + 8*hi) = make_int2(bci(p0), bci(p1));
            }
            // ---- folded Kron(l+1), wave 0 (KL read by B(l+1) after bar2) --
            if (l < 7 && tid < 64) {
                const Gate32* gl2 = gt + (l+1) * 12;
                const int ip = tid >> 3, jp = tid & 7;
                const int i2 = (ip>>2)&1, i1 = (ip>>1)&1, i0 = ip&1;
                const int j2 = (jp>>2)&1, j1 = (jp>>1)&1, j0 = jp&1;
                const C2 kl  = cmul(cmul(gent(gl2[0],i2,j2), gent(gl2[1],i1,j1)), gent(gl2[2],i0,j0));
                const C2 klp = cmul(cmul(gent(gl2[3],i2,j2), gent(gl2[4],i1,j1)), gent(gl2[5],i0,j0));
                const C2 kr  = cmul(cmul(gent(gl2[6],i2,j2), gent(gl2[7],i1,j1)), gent(gl2[8],i0,j0));
                const C2 krp = cmul(cmul(gent(gl2[9],i2,j2), gent(gl2[10],i1,j1)), gent(gl2[11],i0,j0));
                KLr[tid] = kl.r;  KLi[tid] = kl.i;
                KRr[tid] = kr.r;  KRi[tid] = kr.i;
                KLpr[tid] = (f16)klp.r;  KLpi[tid] = (f16)klp.i;
                KRpr[tid] = (f16)krp.r;  KRpi[tid] = (f16)krp.i;
            }
        }
        __syncthreads();                            // bar(2): C -> D
        // ---- phase D: 8 waves = (unit x {W1,W2}); predicated write ----
        {
            const int unit = wid >> 1;              // 0..3
            const int nt2 = unit >> 1, mt2 = unit & 1;
            const int px = wid & 1;                 // 0 = W1 (r1), 1 = W2
            const int r0 = 32*nt2 + lo5;
            const int rr = px ? (r0 ^ 63) : r0;     // U2 = row-flip read
            f16x8 axr[4], axi[4], blr[4], bli[4];
#pragma unroll
            for (int kc = 0; kc < 4; ++kc) {
                const int un = 2*kc + hi;
                axr[kc] = *(const f16x8*)(Ur + moff(rr, un));
                axi[kc] = *(const f16x8*)(Ui + moff(rr, un));
            }
            const int m = 32*mt2 + lo5;
            const int lrow = g6(m);                 // folded row-gray
#pragma unroll
            for (int kc = 0; kc < 4; ++kc) {
                const int un = 2*kc + hi;
                blr[kc] = *(const f16x8*)(Lr + moff(lrow, un));
                bli[kc] = *(const f16x8*)(Li + moff(lrow, un));
            }
            f32x16 wr0 = Z16, wr1 = Z16, wi0 = Z16, wi1 = Z16;
#pragma unroll
            for (int kc = 0; kc < 2; ++kc) {        // k-half 0: chains of 4
                const f16x8 nbli = fneg8(bli[kc]);
                wr0 = MFMA(axr[kc], blr[kc], wr0);
                wr0 = MFMA(axi[kc], nbli,    wr0);
                wi0 = MFMA(axr[kc], bli[kc], wi0);
                wi0 = MFMA(axi[kc], blr[kc], wi0);
            }
#pragma unroll
            for (int kc = 2; kc < 4; ++kc) {        // k-half 1
                const f16x8 nbli = fneg8(bli[kc]);
                wr1 = MFMA(axr[kc], blr[kc], wr1);
                wr1 = MFMA(axi[kc], nbli,    wr1);
                wi1 = MFMA(axr[kc], bli[kc], wi1);
                wi1 = MFMA(axi[kc], blr[kc], wi1);
            }
            const bool mine = ((m & 1) == px);      // parity select, as write
            if (l < 7) {                            // S'[m][n] row-major
                if (mine) {
#pragma unroll
                    for (int gg = 0; gg < 4; ++gg) {
                        const float s0 = wr0[4*gg+0]+wr1[4*gg+0];
                        const float s1 = wr0[4*gg+1]+wr1[4*gg+1];
                        const float s2 = wr0[4*gg+2]+wr1[4*gg+2];
                        const float s3 = wr0[4*gg+3]+wr1[4*gg+3];
                        *(int2*)(Sr + moff(m, 4*nt2+gg) + 8*hi) =
                            make_int2(bci(__floats2half2_rn(s0, s1)),
                                      bci(__floats2half2_rn(s2, s3)));
                        const float t0 = wi0[4*gg+0]+wi1[4*gg+0];
                        const float t1 = wi0[4*gg+1]+wi1[4*gg+1];
                        const float t2 = wi0[4*gg+2]+wi1[4*gg+2];
                        const float t3 = wi0[4*gg+3]+wi1[4*gg+3];
                        *(int2*)(Si + moff(m, 4*nt2+gg) + 8*hi) =
                            make_int2(bci(__floats2half2_rn(t0, t1)),
                                      bci(__floats2half2_rn(t2, t3)));
                    }
                }
            } else {                                // final: f32 global
                if (mine) {
#pragma unroll
                    for (int gg = 0; gg < 4; ++gg)
#pragma unroll
                    for (int e = 0; e < 4; ++e) {
                        const int n = 32*nt2 + 8*gg + 4*hi + e;
                        const int r = 4*gg + e;
                        cols[b*4096 + (m << 6) + n] =
                            make_float2(wr0[r]+wr1[r], wi0[r]+wi1[r]);
                    }
                }
            }
        }
        // no barrier: D reads {U, L[par]}, writes S; next B writes L[par^1],
        // reads KL (written in C, bar(2) between). Next C gated by bar(1).
    }
}

// ---- kernel 2: G-reduce (8 blocks, 1 sample/thread) + quadratic form -----
__global__ __launch_bounds__(1024)
void finish_kernel(const float* __restrict__ sb,
                   const float2* __restrict__ cols,
                   const float* __restrict__ hw,
                   const float* __restrict__ hb,
                   float* __restrict__ out, int B) {
    __shared__ float Gsh[10];
    const int tid  = threadIdx.x;
    const int lane = tid & 63;

    if (tid < 10) Gsh[tid] = 0.f;

    float hwv[12];
#pragma unroll
    for (int w = 0; w < 12; ++w) hwv[w] = hw[w];

    // K(q) split: q = (it<<10) | tid -> Klo over wires 2..11 (bits 9..0)
    float Klo = 0.f;
#pragma unroll
    for (int w = 2; w < 12; ++w)
        Klo += ((tid >> (11 - w)) & 1) ? -hwv[w] : hwv[w];

    __syncthreads();                                // Gsh zero visible

    float g[10];
#pragma unroll
    for (int m = 0; m < 10; ++m) g[m] = 0.f;

#pragma unroll 1
    for (int it = 0; it < 4; ++it) {
        const int q = (it << 10) | tid;
        const float2 c0 = cols[q];
        const float2 c1 = cols[4096  + q];
        const float2 c2 = cols[8192  + q];
        const float2 c3 = cols[12288 + q];
        float K = Klo;
        K += ((it >> 1) & 1) ? -hwv[0] : hwv[0];    // wire 0 <-> bit 11
        K += (it & 1)        ? -hwv[1] : hwv[1];    // wire 1 <-> bit 10
        g[0] += K * (c0.x*c0.x + c0.y*c0.y);
        g[1] += K * (c1.x*c1.x + c1.y*c1.y);
        g[2] += K * (c2.x*c2.x + c2.y*c2.y);
        g[3] += K * (c3.x*c3.x + c3.y*c3.y);
        g[4] += K * (c0.x*c1.x + c0.y*c1.y);
        g[5] += K * (c2.x*c3.x + c2.y*c3.y);
        g[6] += K * (c0.x*c2.y - c0.y*c2.x);
        g[7] += K * (c0.x*c3.y - c0.y*c3.x);
        g[8] += K * (c1.x*c2.y - c1.y*c2.x);
        g[9] += K * (c1.x*c3.y - c1.y*c3.x);
    }

    // wave butterfly -> every lane holds wave-sum; lane m adds to Gsh[m]
#pragma unroll
    for (int m = 0; m < 10; ++m) {
#pragma unroll
        for (int off = 1; off < 64; off <<= 1)
            g[m] += bpermf((lane ^ off) << 2, g[m]);
    }
#pragma unroll
    for (int m = 0; m < 10; ++m)
        if (lane == m) atomicAdd(&Gsh[m], g[m]);
    __syncthreads();

    float G[10];
#pragma unroll
    for (int m = 0; m < 10; ++m)
        G[m] = ((m < 4) ? 1.f : 2.f) * Gsh[m];      // fold 2*Re / 2*Im

    const int i = blockIdx.x * 1024 + tid;
    if (i < B) {
        const float2 x = *reinterpret_cast<const float2*>(sb + i*8);
        float c0, s0, c1, s1;
        __sincosf(0.5f * x.x, &s0, &c0);
        __sincosf(0.5f * x.y, &s1, &c1);
        const float a0 = c0*c1, a1 = c0*s1, a2 = s0*c1, a3 = s0*s1;
        const float r = G[0]*a0*a0 + G[1]*a1*a1 + G[2]*a2*a2 + G[3]*a3*a3
                      + G[4]*(a0*a1) + G[5]*(a2*a3)
                      + G[6]*(a0*a2) + G[7]*(a0*a3)
                      + G[8]*(a1*a2) + G[9]*(a1*a3);
        out[i] = r + hb[0];
    }
}

extern "C" void kernel_launch(void* const* d_in, const int* in_sizes, int n_in,
                              void* d_out, int out_size, void* d_ws, size_t ws_size,
                              hipStream_t stream) {
    const float* sb  = (const float*)d_in[0];
    const float* wts = (const float*)d_in[1];
    const float* hw  = (const float*)d_in[2];
    const float* hb  = (const float*)d_in[3];
    float* out = (float*)d_out;
    float2* cols = (float2*)((char*)d_ws + 4096);       // 128 KB
    const int B = in_sizes[0] / 8;                      // (B,8) state_batch
    sim_kernel   <<<4, 512, 101376, stream>>>(wts, cols);
    finish_kernel<<<(B + 1023)/1024, 1024, 0, stream>>>(sb, cols, hw, hb, out, B);
}